// Round 2
// baseline (841.323 us; speedup 1.0000x reference)
//
#include <hip/hip_runtime.h>
#include <hip/hip_bf16.h>
#include <cstddef>

// Problem constants (fixed by reference)
#define N_USERS   100000
#define N_ITEMS   100000
#define N_NODES   200000
#define D         64
#define BATCH     2048
#define HIST      50
#define N_ITEMS_PAD 100096   // padded to multiple of 128 (block item-chunk)

// Fixed-capacity edge arena: mean deg = 12.8M/200K = 64 (uniform-random rows,
// Poisson tail: P(deg>128) ~ 2e-11 per row on this fixed seed-0 dataset).
#define CAP 128

// k_scores v2 geometry: batch-stationary waves, item-streaming.
#define ISPLITS 92                           // 100096/32 = 3128 tiles = 92 * 34
#define TPS (N_ITEMS_PAD / 32 / ISPLITS)     // 34 item-tiles per x-block

typedef __attribute__((ext_vector_type(8))) short short8;
typedef __attribute__((ext_vector_type(16))) float float16;
typedef __attribute__((ext_vector_type(2)))  float floatx2;

__device__ __forceinline__ ushort f2bf(float x) {  // fp32 -> bf16 RNE
    unsigned u = __float_as_uint(x);
    return (ushort)((u + 0x7FFF + ((u >> 16) & 1)) >> 16);
}
__device__ __forceinline__ unsigned char f2fp8(float x) {  // fp32 -> fp8 e4m3 (OCP), RNE+sat
    int p = __builtin_amdgcn_cvt_pk_fp8_f32(x, x, 0, false);
    return (unsigned char)(p & 0xFF);
}
__device__ __forceinline__ float fp82f(unsigned char u) {  // fp8 e4m3 -> fp32
    return __builtin_amdgcn_cvt_f32_fp8((int)u, 0);
}

// ---------------- direct scatter: build fixed-stride CSR + deg in ONE pass ----------------
// Replaces hist+scan+scatter_a+scatter_b: rows are uniform-random (mean deg 64),
// so a CAP-slot arena + global atomic cursor needs no sort and no staging buffer.
__global__ __launch_bounds__(256) void k_scatter(const int* __restrict__ adj_row,
                                                 const int* __restrict__ adj_col,
                                                 int* __restrict__ deg, int* __restrict__ earena,
                                                 int nedges) {
    int base = blockIdx.x * 1024 + threadIdx.x;
#pragma unroll
    for (int k = 0; k < 4; ++k) {
        int e = base + k * 256;
        if (e < nedges) {
            int r = adj_row[e];
            int c = adj_col[e];
            int pos = atomicAdd(&deg[r], 1);
            if (pos < CAP) earena[(size_t)r * CAP + pos] = c << 6;  // byte offset into fp8 rows
        }
    }
}

// ---------------- init: w0 = fp8( 64 * x0 / sqrt(max(deg,1)) )  (z-space, scaled by 64) ----------------
__global__ void k_init(const float* __restrict__ user_emb, const float* __restrict__ item_emb,
                       const int* __restrict__ deg, unsigned char* __restrict__ w0) {
    int f = blockIdx.x * 256 + threadIdx.x;              // one 4-dim group
    if (f >= N_NODES * (D / 4)) return;
    int row = f >> 4;
    const float4* src = (row < N_USERS)
        ? ((const float4*)user_emb) + (size_t)row * 16 + (f & 15)
        : ((const float4*)item_emb) + (size_t)(row - (N_USERS - 1)) * 16 + (f & 15);
    float4 v = *src;
    int dg = deg[row]; if (dg < 1) dg = 1;
    float sc = 64.f * __frsqrt_rn((float)dg);
    uchar4 o;
    o.x = f2fp8(v.x * sc); o.y = f2fp8(v.y * sc);
    o.z = f2fp8(v.z * sc); o.w = f2fp8(v.w * sc);
    ((uchar4*)w0)[f] = o;
}

// ---------------- propagate (fp8 z-space): w_out[r] = (1/deg_r) * sum w_in[c] ----------------
// v2 lane layout: slot = lane>>3 picks one of 8 edges, d8 = (lane&7)*8 picks 8 dims.
// 8B dwordx2 gathers (half the VMEM of v1) + packed v_cvt_pk_f32_fp8 + float2
// accumulators (v_pk_add_f32) -> ~half the VALU per dim.
__global__ __launch_bounds__(256) void k_prop(const int* __restrict__ deg, const int* __restrict__ earena,
                                              const unsigned char* __restrict__ x_in,
                                              unsigned char* __restrict__ x_out) {
    int w = blockIdx.x * 4 + (threadIdx.x >> 6);
    int lane = threadIdx.x & 63;
    int slot = lane >> 3;
    int d8 = (lane & 7) * 8;
    const unsigned char* xb = x_in + d8;    // loop-invariant base for this lane's dims
    const int* ec = earena + (size_t)w * CAP;
    int cnt = deg[w];
    int lc = (cnt < CAP) ? cnt : CAP;
    floatx2 a01 = {0.f, 0.f}, a23 = {0.f, 0.f}, a45 = {0.f, 0.f}, a67 = {0.f, 0.f};
    int p = 0;
    for (; p + 16 <= lc; p += 16) {
        int c0 = ec[p + slot];
        int c1 = ec[p + 8 + slot];
        uint2 v0 = *(const uint2*)(xb + c0);
        uint2 v1 = *(const uint2*)(xb + c1);
        a01 += __builtin_amdgcn_cvt_pk_f32_fp8((int)v0.x, false);
        a23 += __builtin_amdgcn_cvt_pk_f32_fp8((int)v0.x, true);
        a45 += __builtin_amdgcn_cvt_pk_f32_fp8((int)v0.y, false);
        a67 += __builtin_amdgcn_cvt_pk_f32_fp8((int)v0.y, true);
        a01 += __builtin_amdgcn_cvt_pk_f32_fp8((int)v1.x, false);
        a23 += __builtin_amdgcn_cvt_pk_f32_fp8((int)v1.x, true);
        a45 += __builtin_amdgcn_cvt_pk_f32_fp8((int)v1.y, false);
        a67 += __builtin_amdgcn_cvt_pk_f32_fp8((int)v1.y, true);
    }
    for (; p < lc; p += 8) {
        int rem = lc - p;                      // >= 1
        int sl = (slot < rem) ? slot : 0;
        int c = ec[p + sl];
        uint2 v = *(const uint2*)(xb + c);
        if (slot < rem) {
            a01 += __builtin_amdgcn_cvt_pk_f32_fp8((int)v.x, false);
            a23 += __builtin_amdgcn_cvt_pk_f32_fp8((int)v.x, true);
            a45 += __builtin_amdgcn_cvt_pk_f32_fp8((int)v.y, false);
            a67 += __builtin_amdgcn_cvt_pk_f32_fp8((int)v.y, true);
        }
    }
    // cross-slot reduce: lanes L, L+8, ..., L+56 hold same dims, different edges
#pragma unroll
    for (int off = 32; off >= 8; off >>= 1) {
        a01.x += __shfl_down(a01.x, off); a01.y += __shfl_down(a01.y, off);
        a23.x += __shfl_down(a23.x, off); a23.y += __shfl_down(a23.y, off);
        a45.x += __shfl_down(a45.x, off); a45.y += __shfl_down(a45.y, off);
        a67.x += __shfl_down(a67.x, off); a67.y += __shfl_down(a67.y, off);
    }
    if (lane < 8) {
        float inv = (cnt > 0) ? 1.f / (float)cnt : 0.f;
        int w01 = __builtin_amdgcn_cvt_pk_fp8_f32(a01.x * inv, a01.y * inv, 0, false);
        w01     = __builtin_amdgcn_cvt_pk_fp8_f32(a23.x * inv, a23.y * inv, w01, true);
        int w23 = __builtin_amdgcn_cvt_pk_fp8_f32(a45.x * inv, a45.y * inv, 0, false);
        w23     = __builtin_amdgcn_cvt_pk_fp8_f32(a67.x * inv, a67.y * inv, w23, true);
        uint2 o; o.x = (unsigned)w01; o.y = (unsigned)w23;
        *(uint2*)(x_out + (size_t)w * D + d8) = o;
    }
}

// ---------------- item latents: bf16( 0.25*item_emb + sqrt(deg)/256*(w1+w2+w3) ), zero-pad ----------------
__global__ void k_conv_items(const float* __restrict__ item_emb, const int* __restrict__ deg,
                             const unsigned char* __restrict__ w1, const unsigned char* __restrict__ w2,
                             const unsigned char* __restrict__ w3, ushort* __restrict__ item_bf) {
    int f = blockIdx.x * 256 + threadIdx.x;    // one 4-dim group
    if (f >= N_ITEMS_PAD * (D / 4)) return;
    int row = f >> 4, c4 = f & 15;
    ushort4 o;
    if (row < N_ITEMS) {
        int node = N_USERS + row;
        int dg = deg[node]; if (dg < 1) dg = 1;
        float s = sqrtf((float)dg) * (1.f / 256.f);    // sqrt(deg)/(64 scale * 4 avg)
        float4 e4 = ((const float4*)(item_emb + (size_t)(row + 1) * D))[c4];
        size_t n4 = (size_t)node * 16 + c4;
        uchar4 a = ((const uchar4*)w1)[n4];
        uchar4 b = ((const uchar4*)w2)[n4];
        uchar4 c = ((const uchar4*)w3)[n4];
        o.x = f2bf(0.25f * e4.x + s * (fp82f(a.x) + fp82f(b.x) + fp82f(c.x)));
        o.y = f2bf(0.25f * e4.y + s * (fp82f(a.y) + fp82f(b.y) + fp82f(c.y)));
        o.z = f2bf(0.25f * e4.z + s * (fp82f(a.z) + fp82f(b.z) + fp82f(c.z)));
        o.w = f2bf(0.25f * e4.w + s * (fp82f(a.w) + fp82f(b.w) + fp82f(c.w)));
    } else {
        o.x = o.y = o.z = o.w = 0;   // pad rows -> score 0 -> exp = 1 (subtract 96 in k_loss)
    }
    ((ushort4*)item_bf)[f] = o;
}

// ---------------- pred (bf16 copy) + label score ----------------
__global__ __launch_bounds__(256) void k_pred(const int* __restrict__ user_seqs, const int* __restrict__ his,
                                              const int* __restrict__ next_items,
                                              const float* __restrict__ user_emb, const float* __restrict__ item_emb,
                                              const int* __restrict__ deg,
                                              const unsigned char* __restrict__ w1, const unsigned char* __restrict__ w2,
                                              const unsigned char* __restrict__ w3,
                                              ushort* __restrict__ pred_bf, float* __restrict__ slabel) {
    int b = blockIdx.x * 4 + (threadIdx.x >> 6);
    int lane = threadIdx.x & 63;
    int u = user_seqs[b];
    float hsum = 0.f; int cnt = 0;
    for (int j = 0; j < HIST; ++j) {
        int it = his[b * HIST + j];
        cnt += (it != 0);
        hsum += item_emb[(size_t)it * D + lane];   // item_emb[0] is all-zero (pad)
    }
    int du = deg[u]; if (du < 1) du = 1;
    float su = sqrtf((float)du) * (1.f / 256.f);
    size_t ur = (size_t)u * D + lane;
    float ulat = 0.25f * user_emb[ur] + su * (fp82f(w1[ur]) + fp82f(w2[ur]) + fp82f(w3[ur]));
    float pv = ulat + hsum / (float)cnt;
    pred_bf[(size_t)b * D + lane] = f2bf(pv);
    int lab = next_items[b] - 1;
    int node = N_USERS + lab;
    int di = deg[node]; if (di < 1) di = 1;
    float si = sqrtf((float)di) * (1.f / 256.f);
    size_t nr = (size_t)node * D + lane;
    float ilat = 0.25f * item_emb[(size_t)(lab + 1) * D + lane]
               + si * (fp82f(w1[nr]) + fp82f(w2[nr]) + fp82f(w3[nr]));
    float tv = pv * ilat;
#pragma unroll
    for (int off = 32; off > 0; off >>= 1) tv += __shfl_down(tv, off);
    if (lane == 0) slabel[b] = tv;
}

// ---------------- MFMA scores + max-free sumexp (batch-stationary) ----------------
__global__ __launch_bounds__(256) void k_scores(const ushort* __restrict__ item_bf,
                                                const ushort* __restrict__ pred_bf,
                                                float* __restrict__ sumexp) {
    int t = threadIdx.x, wv = t >> 6, lane = t & 63;
    int l31 = lane & 31;
    int khalf = (lane >> 5) * 8;   // which 8-elem k-half this lane holds

    int brow = blockIdx.y * 128 + wv * 32 + l31;        // this lane's batch column
    const ushort* pb = pred_bf + (size_t)brow * D + khalf;
    short8 b0 = *(const short8*)(pb);
    short8 b1 = *(const short8*)(pb + 16);
    short8 b2 = *(const short8*)(pb + 32);
    short8 b3 = *(const short8*)(pb + 48);

    const ushort* ib = item_bf + ((size_t)blockIdx.x * (TPS * 32) + l31) * D + khalf;
    float acc = 0.f;
    for (int tt = 0; tt < TPS; tt += 2) {
        const ushort* i0 = ib + (size_t)tt * (32 * D);
        const ushort* i1 = i0 + (32 * D);
        short8 a00 = *(const short8*)(i0);
        short8 a01 = *(const short8*)(i0 + 16);
        short8 a02 = *(const short8*)(i0 + 32);
        short8 a03 = *(const short8*)(i0 + 48);
        short8 a10 = *(const short8*)(i1);
        short8 a11 = *(const short8*)(i1 + 16);
        short8 a12 = *(const short8*)(i1 + 32);
        short8 a13 = *(const short8*)(i1 + 48);
        float16 c0 = {0.f};
        float16 c1 = {0.f};
        c0 = __builtin_amdgcn_mfma_f32_32x32x16_bf16(a00, b0, c0, 0, 0, 0);
        c1 = __builtin_amdgcn_mfma_f32_32x32x16_bf16(a10, b0, c1, 0, 0, 0);
        c0 = __builtin_amdgcn_mfma_f32_32x32x16_bf16(a01, b1, c0, 0, 0, 0);
        c1 = __builtin_amdgcn_mfma_f32_32x32x16_bf16(a11, b1, c1, 0, 0, 0);
        c0 = __builtin_amdgcn_mfma_f32_32x32x16_bf16(a02, b2, c0, 0, 0, 0);
        c1 = __builtin_amdgcn_mfma_f32_32x32x16_bf16(a12, b2, c1, 0, 0, 0);
        c0 = __builtin_amdgcn_mfma_f32_32x32x16_bf16(a03, b3, c0, 0, 0, 0);
        c1 = __builtin_amdgcn_mfma_f32_32x32x16_bf16(a13, b3, c1, 0, 0, 0);
        float s0 = 0.f, s1 = 0.f, s2 = 0.f, s3 = 0.f;
#pragma unroll
        for (int r = 0; r < 16; r += 4) {
            s0 += __expf(c0[r]);
            s1 += __expf(c0[r + 1]);
            s2 += __expf(c0[r + 2]);
            s3 += __expf(c0[r + 3]);
        }
#pragma unroll
        for (int r = 0; r < 16; r += 4) {
            s0 += __expf(c1[r]);
            s1 += __expf(c1[r + 1]);
            s2 += __expf(c1[r + 2]);
            s3 += __expf(c1[r + 3]);
        }
        acc += (s0 + s1) + (s2 + s3);
    }
    // lane L and L+32 hold the two item-row halves of the same batch col
    acc += __shfl_down(acc, 32);
    if (lane < 32) unsafeAtomicAdd(&sumexp[brow], acc);
}

// ---------------- final loss reduce ----------------
__global__ __launch_bounds__(256) void k_loss(const float* __restrict__ sumexp, const float* __restrict__ slabel,
                                              float* __restrict__ out) {
    __shared__ float ws[4];
    int t = threadIdx.x;
    float v = 0.f;
    for (int i = t; i < BATCH; i += 256)
        v += __logf(sumexp[i] - 96.0f) - slabel[i];   // -96: padded items contribute exp(0)=1 each
#pragma unroll
    for (int off = 32; off > 0; off >>= 1) v += __shfl_down(v, off);
    if ((t & 63) == 0) ws[t >> 6] = v;
    __syncthreads();
    if (t == 0) out[0] = (ws[0] + ws[1] + ws[2] + ws[3]) * (1.f / (float)BATCH);
}

extern "C" void kernel_launch(void* const* d_in, const int* in_sizes, int n_in,
                              void* d_out, int out_size, void* d_ws, size_t ws_size,
                              hipStream_t stream) {
    const int*   user_seqs = (const int*)d_in[0];
    const int*   his       = (const int*)d_in[1];
    const int*   next_itm  = (const int*)d_in[2];
    const int*   adj_row   = (const int*)d_in[3];
    const int*   adj_col   = (const int*)d_in[4];
    const float* user_emb  = (const float*)d_in[6];
    const float* item_emb  = (const float*)d_in[7];
    float* out = (float*)d_out;
    int nedges = in_sizes[3];   // 12,800,000

    // Workspace layout (~168 MB)
    unsigned char* w0 = (unsigned char*)d_ws;              // 12.8 MB each
    unsigned char* w1 = w0 + (size_t)N_NODES * D;
    unsigned char* w2 = w1 + (size_t)N_NODES * D;
    unsigned char* w3 = w2 + (size_t)N_NODES * D;
    float*  slabel = (float*)(w3 + (size_t)N_NODES * D);   // 2,048
    float*  sumexp = slabel + BATCH;                       // 2,048   (zeroed)
    int*    deg    = (int*)(sumexp + BATCH);               // 200,000 (zeroed)
    int*    earena = deg + N_NODES;                        // 200K * 128 ints (102.4 MB)
    ushort* item_bf = (ushort*)(earena + (size_t)N_NODES * CAP);  // 100096*64 ushort
    ushort* pred_bf = item_bf + (size_t)N_ITEMS_PAD * D;   // 131072 ushort

    // zero sumexp + deg in one shot (contiguous)
    hipError_t _e = hipMemsetAsync(sumexp, 0, (size_t)(BATCH + N_NODES) * sizeof(int), stream);
    (void)_e;

    int nchunks = (nedges + 1023) / 1024;
    k_scatter<<<nchunks, 256, 0, stream>>>(adj_row, adj_col, deg, earena, nedges);

    k_init<<<(N_NODES * (D / 4) + 255) / 256, 256, 0, stream>>>(user_emb, item_emb, deg, w0);

    k_prop<<<N_NODES / 4, 256, 0, stream>>>(deg, earena, w0, w1);
    k_prop<<<N_NODES / 4, 256, 0, stream>>>(deg, earena, w1, w2);
    k_prop<<<N_NODES / 4, 256, 0, stream>>>(deg, earena, w2, w3);

    k_conv_items<<<(N_ITEMS_PAD * (D / 4) + 255) / 256, 256, 0, stream>>>(item_emb, deg, w1, w2, w3, item_bf);
    k_pred<<<BATCH / 4, 256, 0, stream>>>(user_seqs, his, next_itm, user_emb, item_emb, deg,
                                          w1, w2, w3, pred_bf, slabel);

    dim3 gs(ISPLITS, BATCH / 128);
    k_scores<<<gs, 256, 0, stream>>>(item_bf, pred_bf, sumexp);

    k_loss<<<1, 256, 0, stream>>>(sumexp, slabel, out);
}

// Round 3
// 707.995 us; speedup vs baseline: 1.1883x; 1.1883x over previous
//
#include <hip/hip_runtime.h>
#include <hip/hip_bf16.h>
#include <cstddef>

// Problem constants (fixed by reference)
#define N_USERS   100000
#define N_ITEMS   100000
#define N_NODES   200000
#define D         64
#define BATCH     2048
#define HIST      50
#define N_ITEMS_PAD 100096   // padded to multiple of 128 (block item-chunk)

#define BUCKET_SHIFT 9                       // 512 rows per bucket
#define N_BUCKETS ((N_NODES + 511) >> 9)     // 391
#define CHUNK 16384                          // edges per binning block
// Fixed bucket capacity: counts ~ Binomial(12.8M, 512/200K): mean 32768, sigma 181.
// 36864 = mean + 22 sigma. Deterministic seed-0 dataset; guarded per-edge anyway.
#define BCAP 36864

// k_scores geometry: batch-stationary waves, item-streaming.
#define ISPLITS 92                           // 100096/32 = 3128 tiles = 92 * 34
#define TPS (N_ITEMS_PAD / 32 / ISPLITS)     // 34 item-tiles per x-block

typedef __attribute__((ext_vector_type(8))) short short8;
typedef __attribute__((ext_vector_type(16))) float float16;
typedef __attribute__((ext_vector_type(2)))  float floatx2;

__device__ __forceinline__ ushort f2bf(float x) {  // fp32 -> bf16 RNE
    unsigned u = __float_as_uint(x);
    return (ushort)((u + 0x7FFF + ((u >> 16) & 1)) >> 16);
}
__device__ __forceinline__ unsigned char f2fp8(float x) {  // fp32 -> fp8 e4m3 (OCP), RNE+sat
    int p = __builtin_amdgcn_cvt_pk_fp8_f32(x, x, 0, false);
    return (unsigned char)(p & 0xFF);
}
__device__ __forceinline__ float fp82f(unsigned char u) {  // fp8 e4m3 -> fp32
    return __builtin_amdgcn_cvt_f32_fp8((int)u, 0);
}

// ---------------- pass A: bin edges into fixed-capacity bucket arenas ----------------
// staged record = (row&511)<<18 | col  (27 bits). Writes are contiguous runs per
// (bucket, chunk) -> L2-friendly, ~42-edge (~170B) runs. No hist/scan needed:
// bucket base is b*BCAP, cursor starts at 0.
__global__ __launch_bounds__(256) void k_binA(const int* __restrict__ adj_row,
                                              const int* __restrict__ adj_col,
                                              int* __restrict__ gcursor, int* __restrict__ staged,
                                              int nedges) {
    __shared__ int counts[N_BUCKETS];
    __shared__ int cursors[N_BUCKETS];
    int t = threadIdx.x;
    int base = blockIdx.x * CHUNK;
    for (int i = t; i < N_BUCKETS; i += 256) counts[i] = 0;
    __syncthreads();
    for (int k = 0; k < CHUNK / 256; ++k) {
        int e = base + k * 256 + t;
        if (e < nedges) atomicAdd(&counts[adj_row[e] >> BUCKET_SHIFT], 1);
    }
    __syncthreads();
    for (int b = t; b < N_BUCKETS; b += 256) {
        int c = counts[b];
        int s = (c > 0) ? atomicAdd(&gcursor[b], c) : 0;
        cursors[b] = b * BCAP + s;
    }
    __syncthreads();
    for (int k = 0; k < CHUNK / 256; ++k) {
        int e = base + k * 256 + t;
        if (e < nedges) {
            int r = adj_row[e];
            int bkt = r >> BUCKET_SHIFT;
            int p = atomicAdd(&cursors[bkt], 1);
            if (p < (bkt + 1) * BCAP)   // overflow guard (never fires on this data)
                staged[p] = ((r & 511) << 18) | adj_col[e];
        }
    }
}

// ---------------- pass B: per bucket, LDS count+scan -> packed ecols/rowptr/deg; fused init ----------------
// 512 threads: thread t owns row t of the bucket. Also computes
// w0 = fp8(64 * x0 / sqrt(max(deg,1))) for the bucket's 512 rows (init fused).
__global__ __launch_bounds__(512) void k_binB(const int* __restrict__ gcursor, const int* __restrict__ staged,
                                              int* __restrict__ ecols, int* __restrict__ rowptr,
                                              int* __restrict__ deg,
                                              const float* __restrict__ user_emb,
                                              const float* __restrict__ item_emb,
                                              unsigned char* __restrict__ w0) {
    __shared__ int cnt[512];
    __shared__ int scn[512];
    __shared__ int cur[512];
    int b = blockIdx.x, t = threadIdx.x;
    cnt[t] = 0;
    __syncthreads();
    int nb = gcursor[b]; if (nb > BCAP) nb = BCAP;
    size_t es = (size_t)b * BCAP;
    for (int e = t; e < nb; e += 512) atomicAdd(&cnt[staged[es + e] >> 18], 1);
    __syncthreads();
    int myc = cnt[t];
    scn[t] = myc;
    __syncthreads();
    for (int off = 1; off < 512; off <<= 1) {
        int v = (t >= off) ? scn[t - off] : 0;
        __syncthreads();
        scn[t] += v;
        __syncthreads();
    }
    int excl = scn[t] - myc;
    int r = (b << BUCKET_SHIFT) + t;
    int gpos = b * BCAP + excl;
    if (r < N_NODES) { rowptr[r] = gpos; deg[r] = myc; }
    cur[t] = gpos;
    __syncthreads();
    for (int e = t; e < nb; e += 512) {
        int v = staged[es + e];
        int pos = atomicAdd(&cur[v >> 18], 1);
        ecols[pos] = (v & 0x3FFFF) << 6;   // byte offset into fp8 node rows
    }
    // fused init for this bucket's rows (cnt[] is stable; cur/scn unused here)
    int r0 = b << BUCKET_SHIFT;
    for (int f = t; f < 512 * 16; f += 512) {
        int lr = f >> 4;
        int row = r0 + lr;
        if (row >= N_NODES) continue;
        const float4* src = (row < N_USERS)
            ? ((const float4*)user_emb) + (size_t)row * 16 + (f & 15)
            : ((const float4*)item_emb) + (size_t)(row - (N_USERS - 1)) * 16 + (f & 15);
        float4 v = *src;
        int dg = cnt[lr]; if (dg < 1) dg = 1;
        float sc = 64.f * __frsqrt_rn((float)dg);
        uchar4 o;
        o.x = f2fp8(v.x * sc); o.y = f2fp8(v.y * sc);
        o.z = f2fp8(v.z * sc); o.w = f2fp8(v.w * sc);
        ((uchar4*)w0)[(size_t)row * 16 + (f & 15)] = o;
    }
}

// ---------------- propagate (fp8 z-space): w_out[r] = (1/deg_r) * sum w_in[c] ----------------
// 8 lanes/edge x dwordx2 gathers; packed cvt + v_pk_add_f32 accumulators.
// 64-edge block keeps 8 gathers in flight (gather stream misses per-XCD L2:
// x_in = 12.8MB > 4MB, so MLP depth is the latency lever).
#define ACC8(v)                                               \
    a01 += __builtin_amdgcn_cvt_pk_f32_fp8((int)(v).x, false); \
    a23 += __builtin_amdgcn_cvt_pk_f32_fp8((int)(v).x, true);  \
    a45 += __builtin_amdgcn_cvt_pk_f32_fp8((int)(v).y, false); \
    a67 += __builtin_amdgcn_cvt_pk_f32_fp8((int)(v).y, true);

__global__ __launch_bounds__(256) void k_prop(const int* __restrict__ rowptr, const int* __restrict__ deg,
                                              const int* __restrict__ ecols,
                                              const unsigned char* __restrict__ x_in,
                                              unsigned char* __restrict__ x_out) {
    int w = blockIdx.x * 4 + (threadIdx.x >> 6);
    int lane = threadIdx.x & 63;
    int slot = lane >> 3;          // one of 8 edge slots
    int d8 = (lane & 7) * 8;       // 8 dims per lane
    int s = rowptr[w];
    int cnt = deg[w];
    const int* ec = ecols + s;
    floatx2 a01 = {0.f, 0.f}, a23 = {0.f, 0.f}, a45 = {0.f, 0.f}, a67 = {0.f, 0.f};
    int p = 0;
    for (; p + 64 <= cnt; p += 64) {
        int c0 = ec[p + slot];
        int c1 = ec[p + 8 + slot];
        int c2 = ec[p + 16 + slot];
        int c3 = ec[p + 24 + slot];
        int c4 = ec[p + 32 + slot];
        int c5 = ec[p + 40 + slot];
        int c6 = ec[p + 48 + slot];
        int c7 = ec[p + 56 + slot];
        uint2 v0 = *(const uint2*)(x_in + c0 + d8);
        uint2 v1 = *(const uint2*)(x_in + c1 + d8);
        uint2 v2 = *(const uint2*)(x_in + c2 + d8);
        uint2 v3 = *(const uint2*)(x_in + c3 + d8);
        uint2 v4 = *(const uint2*)(x_in + c4 + d8);
        uint2 v5 = *(const uint2*)(x_in + c5 + d8);
        uint2 v6 = *(const uint2*)(x_in + c6 + d8);
        uint2 v7 = *(const uint2*)(x_in + c7 + d8);
        ACC8(v0) ACC8(v1) ACC8(v2) ACC8(v3)
        ACC8(v4) ACC8(v5) ACC8(v6) ACC8(v7)
    }
    for (; p + 32 <= cnt; p += 32) {
        int c0 = ec[p + slot];
        int c1 = ec[p + 8 + slot];
        int c2 = ec[p + 16 + slot];
        int c3 = ec[p + 24 + slot];
        uint2 v0 = *(const uint2*)(x_in + c0 + d8);
        uint2 v1 = *(const uint2*)(x_in + c1 + d8);
        uint2 v2 = *(const uint2*)(x_in + c2 + d8);
        uint2 v3 = *(const uint2*)(x_in + c3 + d8);
        ACC8(v0) ACC8(v1) ACC8(v2) ACC8(v3)
    }
    for (; p < cnt; p += 8) {
        int rem = cnt - p;                     // >= 1
        int sl = (slot < rem) ? slot : 0;
        int c = ec[p + sl];
        uint2 v = *(const uint2*)(x_in + c + d8);
        if (slot < rem) { ACC8(v) }
    }
    // cross-slot reduce: lanes L, L+8, ..., L+56 hold same dims, different edges
#pragma unroll
    for (int off = 32; off >= 8; off >>= 1) {
        a01.x += __shfl_down(a01.x, off); a01.y += __shfl_down(a01.y, off);
        a23.x += __shfl_down(a23.x, off); a23.y += __shfl_down(a23.y, off);
        a45.x += __shfl_down(a45.x, off); a45.y += __shfl_down(a45.y, off);
        a67.x += __shfl_down(a67.x, off); a67.y += __shfl_down(a67.y, off);
    }
    if (lane < 8) {
        float inv = (cnt > 0) ? 1.f / (float)cnt : 0.f;
        int w01 = __builtin_amdgcn_cvt_pk_fp8_f32(a01.x * inv, a01.y * inv, 0, false);
        w01     = __builtin_amdgcn_cvt_pk_fp8_f32(a23.x * inv, a23.y * inv, w01, true);
        int w23 = __builtin_amdgcn_cvt_pk_fp8_f32(a45.x * inv, a45.y * inv, 0, false);
        w23     = __builtin_amdgcn_cvt_pk_fp8_f32(a67.x * inv, a67.y * inv, w23, true);
        uint2 o; o.x = (unsigned)w01; o.y = (unsigned)w23;
        *(uint2*)(x_out + (size_t)w * D + d8) = o;
    }
}

// ---------------- item latents: bf16( 0.25*item_emb + sqrt(deg)/256*(w1+w2+w3) ), zero-pad ----------------
__global__ void k_conv_items(const float* __restrict__ item_emb, const int* __restrict__ deg,
                             const unsigned char* __restrict__ w1, const unsigned char* __restrict__ w2,
                             const unsigned char* __restrict__ w3, ushort* __restrict__ item_bf) {
    int f = blockIdx.x * 256 + threadIdx.x;    // one 4-dim group
    if (f >= N_ITEMS_PAD * (D / 4)) return;
    int row = f >> 4, c4 = f & 15;
    ushort4 o;
    if (row < N_ITEMS) {
        int node = N_USERS + row;
        int dg = deg[node]; if (dg < 1) dg = 1;
        float s = sqrtf((float)dg) * (1.f / 256.f);    // sqrt(deg)/(64 scale * 4 avg)
        float4 e4 = ((const float4*)(item_emb + (size_t)(row + 1) * D))[c4];
        size_t n4 = (size_t)node * 16 + c4;
        uchar4 a = ((const uchar4*)w1)[n4];
        uchar4 b = ((const uchar4*)w2)[n4];
        uchar4 c = ((const uchar4*)w3)[n4];
        o.x = f2bf(0.25f * e4.x + s * (fp82f(a.x) + fp82f(b.x) + fp82f(c.x)));
        o.y = f2bf(0.25f * e4.y + s * (fp82f(a.y) + fp82f(b.y) + fp82f(c.y)));
        o.z = f2bf(0.25f * e4.z + s * (fp82f(a.z) + fp82f(b.z) + fp82f(c.z)));
        o.w = f2bf(0.25f * e4.w + s * (fp82f(a.w) + fp82f(b.w) + fp82f(c.w)));
    } else {
        o.x = o.y = o.z = o.w = 0;   // pad rows -> score 0 -> exp = 1 (subtract 96 in k_loss)
    }
    ((ushort4*)item_bf)[f] = o;
}

// ---------------- pred (bf16 copy) + label score ----------------
__global__ __launch_bounds__(256) void k_pred(const int* __restrict__ user_seqs, const int* __restrict__ his,
                                              const int* __restrict__ next_items,
                                              const float* __restrict__ user_emb, const float* __restrict__ item_emb,
                                              const int* __restrict__ deg,
                                              const unsigned char* __restrict__ w1, const unsigned char* __restrict__ w2,
                                              const unsigned char* __restrict__ w3,
                                              ushort* __restrict__ pred_bf, float* __restrict__ slabel) {
    int b = blockIdx.x * 4 + (threadIdx.x >> 6);
    int lane = threadIdx.x & 63;
    int u = user_seqs[b];
    float hsum = 0.f; int cnt = 0;
    for (int j = 0; j < HIST; ++j) {
        int it = his[b * HIST + j];
        cnt += (it != 0);
        hsum += item_emb[(size_t)it * D + lane];   // item_emb[0] is all-zero (pad)
    }
    int du = deg[u]; if (du < 1) du = 1;
    float su = sqrtf((float)du) * (1.f / 256.f);
    size_t ur = (size_t)u * D + lane;
    float ulat = 0.25f * user_emb[ur] + su * (fp82f(w1[ur]) + fp82f(w2[ur]) + fp82f(w3[ur]));
    float pv = ulat + hsum / (float)cnt;
    pred_bf[(size_t)b * D + lane] = f2bf(pv);
    int lab = next_items[b] - 1;
    int node = N_USERS + lab;
    int di = deg[node]; if (di < 1) di = 1;
    float si = sqrtf((float)di) * (1.f / 256.f);
    size_t nr = (size_t)node * D + lane;
    float ilat = 0.25f * item_emb[(size_t)(lab + 1) * D + lane]
               + si * (fp82f(w1[nr]) + fp82f(w2[nr]) + fp82f(w3[nr]));
    float tv = pv * ilat;
#pragma unroll
    for (int off = 32; off > 0; off >>= 1) tv += __shfl_down(tv, off);
    if (lane == 0) slabel[b] = tv;
}

// ---------------- MFMA scores + max-free sumexp (batch-stationary) ----------------
__global__ __launch_bounds__(256) void k_scores(const ushort* __restrict__ item_bf,
                                                const ushort* __restrict__ pred_bf,
                                                float* __restrict__ sumexp) {
    int t = threadIdx.x, wv = t >> 6, lane = t & 63;
    int l31 = lane & 31;
    int khalf = (lane >> 5) * 8;   // which 8-elem k-half this lane holds

    int brow = blockIdx.y * 128 + wv * 32 + l31;        // this lane's batch column
    const ushort* pb = pred_bf + (size_t)brow * D + khalf;
    short8 b0 = *(const short8*)(pb);
    short8 b1 = *(const short8*)(pb + 16);
    short8 b2 = *(const short8*)(pb + 32);
    short8 b3 = *(const short8*)(pb + 48);

    const ushort* ib = item_bf + ((size_t)blockIdx.x * (TPS * 32) + l31) * D + khalf;
    float acc = 0.f;
    for (int tt = 0; tt < TPS; tt += 2) {
        const ushort* i0 = ib + (size_t)tt * (32 * D);
        const ushort* i1 = i0 + (32 * D);
        short8 a00 = *(const short8*)(i0);
        short8 a01 = *(const short8*)(i0 + 16);
        short8 a02 = *(const short8*)(i0 + 32);
        short8 a03 = *(const short8*)(i0 + 48);
        short8 a10 = *(const short8*)(i1);
        short8 a11 = *(const short8*)(i1 + 16);
        short8 a12 = *(const short8*)(i1 + 32);
        short8 a13 = *(const short8*)(i1 + 48);
        float16 c0 = {0.f};
        float16 c1 = {0.f};
        c0 = __builtin_amdgcn_mfma_f32_32x32x16_bf16(a00, b0, c0, 0, 0, 0);
        c1 = __builtin_amdgcn_mfma_f32_32x32x16_bf16(a10, b0, c1, 0, 0, 0);
        c0 = __builtin_amdgcn_mfma_f32_32x32x16_bf16(a01, b1, c0, 0, 0, 0);
        c1 = __builtin_amdgcn_mfma_f32_32x32x16_bf16(a11, b1, c1, 0, 0, 0);
        c0 = __builtin_amdgcn_mfma_f32_32x32x16_bf16(a02, b2, c0, 0, 0, 0);
        c1 = __builtin_amdgcn_mfma_f32_32x32x16_bf16(a12, b2, c1, 0, 0, 0);
        c0 = __builtin_amdgcn_mfma_f32_32x32x16_bf16(a03, b3, c0, 0, 0, 0);
        c1 = __builtin_amdgcn_mfma_f32_32x32x16_bf16(a13, b3, c1, 0, 0, 0);
        float s0 = 0.f, s1 = 0.f, s2 = 0.f, s3 = 0.f;
#pragma unroll
        for (int r = 0; r < 16; r += 4) {
            s0 += __expf(c0[r]);
            s1 += __expf(c0[r + 1]);
            s2 += __expf(c0[r + 2]);
            s3 += __expf(c0[r + 3]);
        }
#pragma unroll
        for (int r = 0; r < 16; r += 4) {
            s0 += __expf(c1[r]);
            s1 += __expf(c1[r + 1]);
            s2 += __expf(c1[r + 2]);
            s3 += __expf(c1[r + 3]);
        }
        acc += (s0 + s1) + (s2 + s3);
    }
    // lane L and L+32 hold the two item-row halves of the same batch col
    acc += __shfl_down(acc, 32);
    if (lane < 32) unsafeAtomicAdd(&sumexp[brow], acc);
}

// ---------------- final loss reduce ----------------
__global__ __launch_bounds__(256) void k_loss(const float* __restrict__ sumexp, const float* __restrict__ slabel,
                                              float* __restrict__ out) {
    __shared__ float ws[4];
    int t = threadIdx.x;
    float v = 0.f;
    for (int i = t; i < BATCH; i += 256)
        v += __logf(sumexp[i] - 96.0f) - slabel[i];   // -96: padded items contribute exp(0)=1 each
#pragma unroll
    for (int off = 32; off > 0; off >>= 1) v += __shfl_down(v, off);
    if ((t & 63) == 0) ws[t >> 6] = v;
    __syncthreads();
    if (t == 0) out[0] = (ws[0] + ws[1] + ws[2] + ws[3]) * (1.f / (float)BATCH);
}

extern "C" void kernel_launch(void* const* d_in, const int* in_sizes, int n_in,
                              void* d_out, int out_size, void* d_ws, size_t ws_size,
                              hipStream_t stream) {
    const int*   user_seqs = (const int*)d_in[0];
    const int*   his       = (const int*)d_in[1];
    const int*   next_itm  = (const int*)d_in[2];
    const int*   adj_row   = (const int*)d_in[3];
    const int*   adj_col   = (const int*)d_in[4];
    const float* user_emb  = (const float*)d_in[6];
    const float* item_emb  = (const float*)d_in[7];
    float* out = (float*)d_out;
    int nedges = in_sizes[3];   // 12,800,000

    // Workspace layout (~183 MB)
    unsigned char* w0 = (unsigned char*)d_ws;              // 12.8 MB each
    unsigned char* w1 = w0 + (size_t)N_NODES * D;
    unsigned char* w2 = w1 + (size_t)N_NODES * D;
    unsigned char* w3 = w2 + (size_t)N_NODES * D;
    float*  slabel = (float*)(w3 + (size_t)N_NODES * D);   // 2,048
    float*  sumexp = slabel + BATCH;                       // 2,048   (zeroed)
    int*    gcursor= (int*)(sumexp + BATCH);               // 391     (zeroed)
    int*    rowptr = gcursor + N_BUCKETS;                  // 200,000
    int*    deg    = rowptr + N_NODES;                     // 200,000
    int*    staged = deg + N_NODES;                        // 391*36864 ints (57.7 MB)
    int*    ecols  = staged + (size_t)N_BUCKETS * BCAP;    // 391*36864 ints (57.7 MB)
    ushort* item_bf = (ushort*)(ecols + (size_t)N_BUCKETS * BCAP);  // 100096*64 ushort
    ushort* pred_bf = item_bf + (size_t)N_ITEMS_PAD * D;   // 131072 ushort

    // zero sumexp + gcursor in one shot (contiguous)
    hipError_t _e = hipMemsetAsync(sumexp, 0, (size_t)(BATCH + N_BUCKETS) * sizeof(int), stream);
    (void)_e;

    int nchunks = (nedges + CHUNK - 1) / CHUNK;
    k_binA<<<nchunks, 256, 0, stream>>>(adj_row, adj_col, gcursor, staged, nedges);
    k_binB<<<N_BUCKETS, 512, 0, stream>>>(gcursor, staged, ecols, rowptr, deg,
                                          user_emb, item_emb, w0);

    k_prop<<<N_NODES / 4, 256, 0, stream>>>(rowptr, deg, ecols, w0, w1);
    k_prop<<<N_NODES / 4, 256, 0, stream>>>(rowptr, deg, ecols, w1, w2);
    k_prop<<<N_NODES / 4, 256, 0, stream>>>(rowptr, deg, ecols, w2, w3);

    k_conv_items<<<(N_ITEMS_PAD * (D / 4) + 255) / 256, 256, 0, stream>>>(item_emb, deg, w1, w2, w3, item_bf);
    k_pred<<<BATCH / 4, 256, 0, stream>>>(user_seqs, his, next_itm, user_emb, item_emb, deg,
                                          w1, w2, w3, pred_bf, slabel);

    dim3 gs(ISPLITS, BATCH / 128);
    k_scores<<<gs, 256, 0, stream>>>(item_bf, pred_bf, sumexp);

    k_loss<<<1, 256, 0, stream>>>(sumexp, slabel, out);
}